// Round 7
// baseline (467.871 us; speedup 1.0000x reference)
//
#include <hip/hip_runtime.h>

// ---------------------------------------------------------------------------
// Petri_GCN: 3x GCNConv(64->64) + MLP readout (64->32->1) + segment-mean pool
// All fp32 (abs threshold forbids bf16/MFMA; no fp32 MFMA on CDNA4).
// R1: CSR-by-dst + gather instead of atomic scatter.
// R2: readout wave-segmented atomics; gather 4x(16-lane x float4) layout.
// R3: count-only atomic pass; Ts=(X@W)*dinv epilogue; gather pure-write.
// R4: gemm launch_bounds(256,2) + no __restrict__ (partial fix: stopped the
//     FETCH blowup, W reloads moved to L1, still 82us).
// R5: bucketed 2-phase CSR build (fill 125us+cnt 65us -> ~60us total).
// R6: gemm W-residency made compiler-proof: asm "+v" pin on the 64 W values.
//     R6 counters showed VGPR=44 (wc[] NOT in registers, reloaded from L1
//     every row; latency-bound 82us, VALUBusy 13%). Opaque asm def forbids
//     rematerialization -> must stay in VGPRs.
// ---------------------------------------------------------------------------

#define NBK 391          // ceil(100000/256) buckets; arrays padded to 512

// LDS histogram of dst>>8, merged to global.
__global__ void hist_kernel(const int* __restrict__ dst,
                            int* __restrict__ bcnt, int ne) {
    __shared__ int h[512];
    for (int i = threadIdx.x; i < 512; i += blockDim.x) h[i] = 0;
    __syncthreads();
    int stride = gridDim.x * blockDim.x;
    for (int e = blockIdx.x * blockDim.x + threadIdx.x; e < ne; e += stride)
        atomicAdd(&h[dst[e] >> 8], 1);
    __syncthreads();
    for (int i = threadIdx.x; i < 512; i += blockDim.x)
        if (h[i]) atomicAdd(&bcnt[i], h[i]);
}

// One block: exclusive scan of bucket counts -> bbase[0..nb], seed gcur.
__global__ void bscan_kernel(const int* __restrict__ bcnt,
                             int* __restrict__ bbase,
                             int* __restrict__ gcur, int nb, int ne) {
    __shared__ int sh[512];
    int t = threadIdx.x;
    int v = (t < nb) ? bcnt[t] : 0;
    sh[t] = v;
    __syncthreads();
    for (int off = 1; off < 512; off <<= 1) {
        int u = (t >= off) ? sh[t - off] : 0;
        __syncthreads();
        sh[t] += u;
        __syncthreads();
    }
    if (t < nb) {
        int e = sh[t] - v;
        bbase[t] = e;
        gcur[t] = e;
    }
    if (t == 0) bbase[nb] = ne;
}

// Redistribute edges into bucket regions. Per-WG: LDS chunk histogram,
// one global atomic per touched bucket reserves a dense run, LDS cursors
// place edges. packed = {(local8<<24)|src17, w}.
__global__ void scatterB_kernel(const int* __restrict__ src,
                                const int* __restrict__ dst,
                                const float* __restrict__ ew,
                                int* __restrict__ gcur,
                                int2* __restrict__ packed, int ne) {
    __shared__ int h[512];
    __shared__ int cur[512];
    int chunk = (ne + gridDim.x - 1) / gridDim.x;
    int e0 = blockIdx.x * chunk;
    int e1 = e0 + chunk; if (e1 > ne) e1 = ne;
    for (int i = threadIdx.x; i < 512; i += blockDim.x) h[i] = 0;
    __syncthreads();
    for (int e = e0 + threadIdx.x; e < e1; e += blockDim.x)
        atomicAdd(&h[dst[e] >> 8], 1);
    __syncthreads();
    for (int i = threadIdx.x; i < 512; i += blockDim.x)
        cur[i] = h[i] ? atomicAdd(&gcur[i], h[i]) : 0;
    __syncthreads();
    for (int e = e0 + threadIdx.x; e < e1; e += blockDim.x) {
        int d = dst[e];
        int pos = atomicAdd(&cur[d >> 8], 1);   // LDS atomic
        int2 v;
        v.x = ((d & 255) << 24) | src[e];       // src < 2^17, fits
        v.y = __float_as_int(ew[e]);
        packed[pos] = v;
    }
}

// One WG per bucket (256 nodes). Count per node in LDS, LDS scan -> rptr/cnt,
// scatter final CSR within the bucket's own window (L2-hot), then per-thread
// sequential row-sum of w -> dinv. No global atomics anywhere.
__global__ void bucket_build_kernel(const int2* __restrict__ packed,
                                    const int* __restrict__ bbase,
                                    int* __restrict__ rptr,
                                    int* __restrict__ cnt,
                                    float* __restrict__ dinv,
                                    int2* __restrict__ csr, int n) {
    __shared__ int cl[256];
    __shared__ int sc[256];
    __shared__ int cur[256];
    int b = blockIdx.x;
    int t = threadIdx.x;
    int node0 = b << 8;
    int nn = n - node0; if (nn > 256) nn = 256;
    int ebase = bbase[b];
    int m = bbase[b + 1] - ebase;
    cl[t] = 0;
    __syncthreads();
    for (int j = t; j < m; j += 256) {
        int local = ((unsigned)packed[ebase + j].x) >> 24;
        atomicAdd(&cl[local], 1);               // LDS atomic
    }
    __syncthreads();
    int c = cl[t];
    sc[t] = c;
    __syncthreads();
    for (int off = 1; off < 256; off <<= 1) {
        int u = (t >= off) ? sc[t - off] : 0;
        __syncthreads();
        sc[t] += u;
        __syncthreads();
    }
    int base = ebase + sc[t] - c;               // global CSR row start
    cur[t] = base;
    if (t < nn) {
        rptr[node0 + t] = base;
        cnt[node0 + t] = c;
    }
    __syncthreads();
    for (int j = t; j < m; j += 256) {
        int2 p = packed[ebase + j];
        int local = ((unsigned)p.x) >> 24;
        int pos = atomicAdd(&cur[local], 1);    // LDS atomic
        int2 v;
        v.x = p.x & 0x00FFFFFF;
        v.y = p.y;
        csr[pos] = v;
    }
    __syncthreads();
    if (t < nn) {
        float s = 0.0f;
        for (int j = base; j < base + c; ++j)
            s += __int_as_float(csr[j].y);
        dinv[node0 + t] = 1.0f / sqrtf(s + 1.0f);
    }
}

// One wave per row. Lane c holds W[:,c] in 64 VGPRs (asm-pinned: opaque def
// forbids rematerialization -- R6 showed VGPR=44 = W reloaded per row from
// L1, 82us latency-bound). X row read as uniform float4 broadcasts.
// Single store: Ts = act(X)@W * dinv[r]. X aliases A across layers.
template <bool RELU>
__global__ void __launch_bounds__(256, 2)
gemm_ts_kernel(const float* X, const float* W,
               const float* __restrict__ dinv,
               float* Ts, int n) {
    int lane = threadIdx.x & 63;
    int wid  = (blockIdx.x * blockDim.x + threadIdx.x) >> 6;
    int nw   = (gridDim.x * blockDim.x) >> 6;
    float4 wc4[16];
#pragma unroll
    for (int k = 0; k < 16; ++k) {
        float4 v;
        v.x = W[(4 * k + 0) * 64 + lane];
        v.y = W[(4 * k + 1) * 64 + lane];
        v.z = W[(4 * k + 2) * 64 + lane];
        v.w = W[(4 * k + 3) * 64 + lane];
        wc4[k] = v;
    }
#pragma unroll
    for (int k = 0; k < 16; ++k)
        asm volatile("" : "+v"(wc4[k].x), "+v"(wc4[k].y),
                          "+v"(wc4[k].z), "+v"(wc4[k].w));
    for (int r = wid; r < n; r += nw) {
        const float4* xr = (const float4*)(X + (size_t)r * 64);
        float acc = 0.0f;
#pragma unroll
        for (int k4 = 0; k4 < 16; ++k4) {
            float4 x4 = xr[k4];
            if (RELU) {
                x4.x = fmaxf(x4.x, 0.0f); x4.y = fmaxf(x4.y, 0.0f);
                x4.z = fmaxf(x4.z, 0.0f); x4.w = fmaxf(x4.w, 0.0f);
            }
            acc = fmaf(x4.x, wc4[k4].x, acc);
            acc = fmaf(x4.y, wc4[k4].y, acc);
            acc = fmaf(x4.z, wc4[k4].z, acc);
            acc = fmaf(x4.w, wc4[k4].w, acc);
        }
        Ts[(size_t)r * 64 + lane] = acc * dinv[r];
    }
}

// One wave per dst row. 4 subgroups of 16 lanes; subgroup handles every 4th
// edge; lane's float4 covers channels 4*cl..4*cl+3. One dwordx4 VMEM instr
// serves 4 edges. A[r] = dinv[r]*(sum + Ts[r]) + b  (pure write).
__global__ void gather_kernel(const int2* __restrict__ csr,
                              const int* __restrict__ rptr,
                              const int* __restrict__ cnt,
                              const float* __restrict__ dinv,
                              const float* __restrict__ b,
                              const float* __restrict__ Ts,
                              float* __restrict__ A, int n) {
    int lane = threadIdx.x & 63;
    int r = (int)(((size_t)blockIdx.x * blockDim.x + threadIdx.x) >> 6);
    if (r >= n) return;
    int sub = lane >> 4;          // 0..3: edge subgroup
    int cl  = lane & 15;          // channel quad
    int start = rptr[r];
    int m = cnt[r];
    float4 a0 = {0.f, 0.f, 0.f, 0.f};
    float4 a1 = {0.f, 0.f, 0.f, 0.f};
    int j = sub;
    for (; j + 4 < m; j += 8) {
        int2 e0 = csr[start + j];
        int2 e1 = csr[start + j + 4];
        float w0 = __int_as_float(e0.y);
        float w1 = __int_as_float(e1.y);
        float4 t0 = *(const float4*)&Ts[(size_t)e0.x * 64 + cl * 4];
        float4 t1 = *(const float4*)&Ts[(size_t)e1.x * 64 + cl * 4];
        a0.x = fmaf(t0.x, w0, a0.x); a0.y = fmaf(t0.y, w0, a0.y);
        a0.z = fmaf(t0.z, w0, a0.z); a0.w = fmaf(t0.w, w0, a0.w);
        a1.x = fmaf(t1.x, w1, a1.x); a1.y = fmaf(t1.y, w1, a1.y);
        a1.z = fmaf(t1.z, w1, a1.z); a1.w = fmaf(t1.w, w1, a1.w);
    }
    if (j < m) {
        int2 e0 = csr[start + j];
        float w0 = __int_as_float(e0.y);
        float4 t0 = *(const float4*)&Ts[(size_t)e0.x * 64 + cl * 4];
        a0.x = fmaf(t0.x, w0, a0.x); a0.y = fmaf(t0.y, w0, a0.y);
        a0.z = fmaf(t0.z, w0, a0.z); a0.w = fmaf(t0.w, w0, a0.w);
    }
    a0.x += a1.x; a0.y += a1.y; a0.z += a1.z; a0.w += a1.w;
#pragma unroll
    for (int off = 16; off < 64; off <<= 1) {
        a0.x += __shfl_xor(a0.x, off);
        a0.y += __shfl_xor(a0.y, off);
        a0.z += __shfl_xor(a0.z, off);
        a0.w += __shfl_xor(a0.w, off);
    }
    if (sub == 0) {
        float dv = dinv[r];
        float4 ts = *(const float4*)&Ts[(size_t)r * 64 + cl * 4];
        float4 bb = *(const float4*)&b[cl * 4];
        float4 o;
        o.x = fmaf(dv, a0.x + ts.x, bb.x);
        o.y = fmaf(dv, a0.y + ts.y, bb.y);
        o.z = fmaf(dv, a0.z + ts.z, bb.z);
        o.w = fmaf(dv, a0.w + ts.w, bb.w);
        *(float4*)&A[(size_t)r * 64 + cl * 4] = o;
    }
}

// Thread per node: sv = relu(h @ Wr0 + br0) @ Wr1 + br1.
// batch is sorted -> wave-segmented suffix reduction, heads do the atomics.
__global__ void readout_kernel(const float* __restrict__ H,
                               const float* __restrict__ Wr0,
                               const float* __restrict__ br0,
                               const float* __restrict__ Wr1,
                               const float* __restrict__ br1,
                               const int* __restrict__ batch,
                               float* __restrict__ gsum,
                               float* __restrict__ gcnt, int n) {
    __shared__ float Ws[64 * 32];
    __shared__ float w1s[32];
    for (int i = threadIdx.x; i < 64 * 32; i += blockDim.x) Ws[i] = Wr0[i];
    if (threadIdx.x < 32) w1s[threadIdx.x] = Wr1[threadIdx.x];
    __syncthreads();
    int r = blockIdx.x * blockDim.x + threadIdx.x;
    int lane = threadIdx.x & 63;
    float sv = 0.0f;
    int g = -1;
    if (r < n) {
        float h[64];
        const float4* hr = (const float4*)(H + (size_t)r * 64);
#pragma unroll
        for (int i = 0; i < 16; ++i) {
            float4 v = hr[i];
            h[4 * i + 0] = v.x; h[4 * i + 1] = v.y;
            h[4 * i + 2] = v.z; h[4 * i + 3] = v.w;
        }
        float ssum = 0.0f;
#pragma unroll 1
        for (int jg = 0; jg < 8; ++jg) {
            float a0 = br0[jg * 4 + 0], a1 = br0[jg * 4 + 1];
            float a2 = br0[jg * 4 + 2], a3 = br0[jg * 4 + 3];
#pragma unroll
            for (int k = 0; k < 64; ++k) {
                const float4 wv = *(const float4*)&Ws[k * 32 + jg * 4];
                a0 = fmaf(h[k], wv.x, a0);
                a1 = fmaf(h[k], wv.y, a1);
                a2 = fmaf(h[k], wv.z, a2);
                a3 = fmaf(h[k], wv.w, a3);
            }
            a0 = fmaxf(a0, 0.0f); a1 = fmaxf(a1, 0.0f);
            a2 = fmaxf(a2, 0.0f); a3 = fmaxf(a3, 0.0f);
            ssum += a0 * w1s[jg * 4 + 0] + a1 * w1s[jg * 4 + 1] +
                    a2 * w1s[jg * 4 + 2] + a3 * w1s[jg * 4 + 3];
        }
        sv = ssum + br1[0];
        g = batch[r];
    }
    float c = (r < n) ? 1.0f : 0.0f;
#pragma unroll
    for (int off = 1; off < 64; off <<= 1) {
        int   og = __shfl_down(g, off);
        float ov = __shfl_down(sv, off);
        float oc = __shfl_down(c, off);
        if ((lane + off) < 64 && og == g) { sv += ov; c += oc; }
    }
    int gprev = __shfl_up(g, 1);
    bool head = (lane == 0) || (gprev != g);
    if (head && g >= 0) {
        atomicAdd(&gsum[g], sv);
        atomicAdd(&gcnt[g], c);
    }
}

__global__ void pool_fin_kernel(const float* __restrict__ gsum,
                                const float* __restrict__ gcnt,
                                float* __restrict__ out, int ng) {
    int g = blockIdx.x * blockDim.x + threadIdx.x;
    if (g < ng) out[g] = gsum[g] / fmaxf(gcnt[g], 1.0f);
}

extern "C" void kernel_launch(void* const* d_in, const int* in_sizes, int n_in,
                              void* d_out, int out_size, void* d_ws, size_t ws_size,
                              hipStream_t stream) {
    const float* x    = (const float*)d_in[0];
    const int*   ei   = (const int*)d_in[1];
    const float* ew   = (const float*)d_in[2];
    const int*   batch= (const int*)d_in[3];
    const float* W0   = (const float*)d_in[4];
    const float* b0   = (const float*)d_in[5];
    const float* W1   = (const float*)d_in[6];
    const float* b1   = (const float*)d_in[7];
    const float* W2   = (const float*)d_in[8];
    const float* b2   = (const float*)d_in[9];
    const float* Wr0  = (const float*)d_in[10];
    const float* br0  = (const float*)d_in[11];
    const float* Wr1  = (const float*)d_in[12];
    const float* br1  = (const float*)d_in[13];
    float* out = (float*)d_out;

    int n  = in_sizes[0] / 64;   // 100000
    int ne = in_sizes[1] / 2;    // 1600000
    int ng = out_size;           // 256
    const int* srcv = ei;
    const int* dstv = ei + ne;
    int nbk = (n + 255) >> 8;    // 391

    char* ws = (char*)d_ws;
    size_t off = 0;
    auto alloc = [&](size_t bytes) {
        void* p = ws + off;
        off += (bytes + 255) & ~(size_t)255;
        return p;
    };
    float* Ts     = (float*)alloc((size_t)n * 64 * sizeof(float));
    float* A      = (float*)alloc((size_t)n * 64 * sizeof(float));
    float* dinv   = (float*)alloc((size_t)n * sizeof(float));
    int*   cnt    = (int*)alloc((size_t)n * sizeof(int));
    int*   rptr   = (int*)alloc((size_t)n * sizeof(int));
    int*   bcnt   = (int*)alloc(520 * sizeof(int));
    int*   bbase  = (int*)alloc(520 * sizeof(int));
    int*   gcur   = (int*)alloc(520 * sizeof(int));
    int2*  csr    = (int2*)alloc((size_t)ne * sizeof(int2));
    float* gsum   = (float*)alloc((size_t)ng * sizeof(float));
    float* gcnt   = (float*)alloc((size_t)ng * sizeof(float));
    // packed aliases Ts: consumed by bucket_build before first gemm writes Ts.
    int2*  packed = (int2*)Ts;
    (void)ws_size;

    hipMemsetAsync(bcnt, 0, 520 * sizeof(int), stream);
    hipMemsetAsync(gsum, 0, (size_t)ng * sizeof(float), stream);
    hipMemsetAsync(gcnt, 0, (size_t)ng * sizeof(float), stream);

    hist_kernel<<<256, 256, 0, stream>>>(dstv, bcnt, ne);
    bscan_kernel<<<1, 512, 0, stream>>>(bcnt, bbase, gcur, nbk, ne);
    scatterB_kernel<<<200, 256, 0, stream>>>(srcv, dstv, ew, gcur, packed, ne);
    bucket_build_kernel<<<nbk, 256, 0, stream>>>(packed, bbase, rptr, cnt,
                                                 dinv, csr, n);

    const int gemm_blocks = 1024;
    unsigned gat_blocks = (unsigned)(((size_t)n * 64 + 255) / 256);

    gemm_ts_kernel<false><<<gemm_blocks, 256, 0, stream>>>(x, W0, dinv, Ts, n);
    gather_kernel<<<gat_blocks, 256, 0, stream>>>(csr, rptr, cnt, dinv, b0, Ts, A, n);

    gemm_ts_kernel<true><<<gemm_blocks, 256, 0, stream>>>(A, W1, dinv, Ts, n);
    gather_kernel<<<gat_blocks, 256, 0, stream>>>(csr, rptr, cnt, dinv, b1, Ts, A, n);

    gemm_ts_kernel<true><<<gemm_blocks, 256, 0, stream>>>(A, W2, dinv, Ts, n);
    gather_kernel<<<gat_blocks, 256, 0, stream>>>(csr, rptr, cnt, dinv, b2, Ts, A, n);

    readout_kernel<<<(n + 255) / 256, 256, 0, stream>>>(A, Wr0, br0, Wr1, br1,
                                                        batch, gsum, gcnt, n);
    pool_fin_kernel<<<(ng + 255) / 256, 256, 0, stream>>>(gsum, gcnt, out, ng);
}

// Round 8
// 450.785 us; speedup vs baseline: 1.0379x; 1.0379x over previous
//
#include <hip/hip_runtime.h>

// ---------------------------------------------------------------------------
// Petri_GCN: 3x GCNConv(64->64) + MLP readout (64->32->1) + segment-mean pool
// All fp32 (abs threshold forbids bf16/MFMA; no fp32 MFMA on CDNA4).
// R1: CSR-by-dst + gather instead of atomic scatter.
// R2: readout wave-segmented atomics; gather 4x(16-lane x float4) layout.
// R3: count-only atomic pass; Ts=(X@W)*dinv epilogue; gather pure-write.
// R5: bucketed 2-phase CSR build (fill 125us + cnt 65us -> ~60us total).
// R4/R6/R7: tried to force W into 64 VGPRs/lane (no-restrict, launch_bounds,
//     asm "+v" pin). ALL FAILED: allocator kept VGPR=44 and refetched W per
//     row (latency-bound 82us, VALUBusy 13%). Lesson: don't fight the
//     allocator for 64-deep per-lane arrays.
// R8: W in LDS (16KB, staged once/block) + 4-row unroll. ds_read W[k][lane]
//     is bank-conflict-free (bank=lane%32, 2 lanes/bank = free), ~30cyc
//     latency, each read amortized over 4 rows' FMAs; 4x MLP on X loads.
// ---------------------------------------------------------------------------

#define NBK 391          // ceil(100000/256) buckets; arrays padded to 512

// LDS histogram of dst>>8, merged to global.
__global__ void hist_kernel(const int* __restrict__ dst,
                            int* __restrict__ bcnt, int ne) {
    __shared__ int h[512];
    for (int i = threadIdx.x; i < 512; i += blockDim.x) h[i] = 0;
    __syncthreads();
    int stride = gridDim.x * blockDim.x;
    for (int e = blockIdx.x * blockDim.x + threadIdx.x; e < ne; e += stride)
        atomicAdd(&h[dst[e] >> 8], 1);
    __syncthreads();
    for (int i = threadIdx.x; i < 512; i += blockDim.x)
        if (h[i]) atomicAdd(&bcnt[i], h[i]);
}

// One block: exclusive scan of bucket counts -> bbase[0..nb], seed gcur.
__global__ void bscan_kernel(const int* __restrict__ bcnt,
                             int* __restrict__ bbase,
                             int* __restrict__ gcur, int nb, int ne) {
    __shared__ int sh[512];
    int t = threadIdx.x;
    int v = (t < nb) ? bcnt[t] : 0;
    sh[t] = v;
    __syncthreads();
    for (int off = 1; off < 512; off <<= 1) {
        int u = (t >= off) ? sh[t - off] : 0;
        __syncthreads();
        sh[t] += u;
        __syncthreads();
    }
    if (t < nb) {
        int e = sh[t] - v;
        bbase[t] = e;
        gcur[t] = e;
    }
    if (t == 0) bbase[nb] = ne;
}

// Redistribute edges into bucket regions. Per-WG: LDS chunk histogram,
// one global atomic per touched bucket reserves a dense run, LDS cursors
// place edges. packed = {(local8<<24)|src17, w}.
__global__ void scatterB_kernel(const int* __restrict__ src,
                                const int* __restrict__ dst,
                                const float* __restrict__ ew,
                                int* __restrict__ gcur,
                                int2* __restrict__ packed, int ne) {
    __shared__ int h[512];
    __shared__ int cur[512];
    int chunk = (ne + gridDim.x - 1) / gridDim.x;
    int e0 = blockIdx.x * chunk;
    int e1 = e0 + chunk; if (e1 > ne) e1 = ne;
    for (int i = threadIdx.x; i < 512; i += blockDim.x) h[i] = 0;
    __syncthreads();
    for (int e = e0 + threadIdx.x; e < e1; e += blockDim.x)
        atomicAdd(&h[dst[e] >> 8], 1);
    __syncthreads();
    for (int i = threadIdx.x; i < 512; i += blockDim.x)
        cur[i] = h[i] ? atomicAdd(&gcur[i], h[i]) : 0;
    __syncthreads();
    for (int e = e0 + threadIdx.x; e < e1; e += blockDim.x) {
        int d = dst[e];
        int pos = atomicAdd(&cur[d >> 8], 1);   // LDS atomic
        int2 v;
        v.x = ((d & 255) << 24) | src[e];       // src < 2^17, fits
        v.y = __float_as_int(ew[e]);
        packed[pos] = v;
    }
}

// One WG per bucket (256 nodes). Count per node in LDS, LDS scan -> rptr/cnt,
// scatter final CSR within the bucket's own window (L2-hot), then per-thread
// sequential row-sum of w -> dinv. No global atomics anywhere.
__global__ void bucket_build_kernel(const int2* __restrict__ packed,
                                    const int* __restrict__ bbase,
                                    int* __restrict__ rptr,
                                    int* __restrict__ cnt,
                                    float* __restrict__ dinv,
                                    int2* __restrict__ csr, int n) {
    __shared__ int cl[256];
    __shared__ int sc[256];
    __shared__ int cur[256];
    int b = blockIdx.x;
    int t = threadIdx.x;
    int node0 = b << 8;
    int nn = n - node0; if (nn > 256) nn = 256;
    int ebase = bbase[b];
    int m = bbase[b + 1] - ebase;
    cl[t] = 0;
    __syncthreads();
    for (int j = t; j < m; j += 256) {
        int local = ((unsigned)packed[ebase + j].x) >> 24;
        atomicAdd(&cl[local], 1);               // LDS atomic
    }
    __syncthreads();
    int c = cl[t];
    sc[t] = c;
    __syncthreads();
    for (int off = 1; off < 256; off <<= 1) {
        int u = (t >= off) ? sc[t - off] : 0;
        __syncthreads();
        sc[t] += u;
        __syncthreads();
    }
    int base = ebase + sc[t] - c;               // global CSR row start
    cur[t] = base;
    if (t < nn) {
        rptr[node0 + t] = base;
        cnt[node0 + t] = c;
    }
    __syncthreads();
    for (int j = t; j < m; j += 256) {
        int2 p = packed[ebase + j];
        int local = ((unsigned)p.x) >> 24;
        int pos = atomicAdd(&cur[local], 1);    // LDS atomic
        int2 v;
        v.x = p.x & 0x00FFFFFF;
        v.y = p.y;
        csr[pos] = v;
    }
    __syncthreads();
    if (t < nn) {
        float s = 0.0f;
        for (int j = base; j < base + c; ++j)
            s += __int_as_float(csr[j].y);
        dinv[node0 + t] = 1.0f / sqrtf(s + 1.0f);
    }
}

// GEMM: W staged in LDS (16KB); each wave processes 4 rows per iteration.
// Lane = output column. W read per k as ds_read (bank = lane%32: 2 lanes/
// bank = conflict-free), amortized over 4 rows. X rows read as uniform
// float4 broadcasts (4 independent streams = 4x MLP).
// Ts = act(X)@W * dinv[r].  X aliases A across layers (row fully read
// before any wave writes it; rows wave-exclusive... Ts != A always).
template <bool RELU>
__global__ void __launch_bounds__(256, 4)
gemm_lds_kernel(const float* X, const float* W,
                const float* __restrict__ dinv, float* Ts, int n) {
    __shared__ float Wl[4096];
    {
        const float4* Wv = (const float4*)W;
        float4* Lv = (float4*)Wl;
        for (int i = threadIdx.x; i < 1024; i += 256) Lv[i] = Wv[i];
    }
    __syncthreads();
    int lane = threadIdx.x & 63;
    int wid  = (blockIdx.x * blockDim.x + threadIdx.x) >> 6;
    int nw   = (gridDim.x * blockDim.x) >> 6;
    for (int r0 = wid * 4; r0 < n; r0 += nw * 4) {
        if (r0 + 4 <= n) {
            const float4* x0 = (const float4*)(X + (size_t)(r0 + 0) * 64);
            const float4* x1 = (const float4*)(X + (size_t)(r0 + 1) * 64);
            const float4* x2 = (const float4*)(X + (size_t)(r0 + 2) * 64);
            const float4* x3 = (const float4*)(X + (size_t)(r0 + 3) * 64);
            float acc0 = 0.f, acc1 = 0.f, acc2 = 0.f, acc3 = 0.f;
#pragma unroll
            for (int k4 = 0; k4 < 16; ++k4) {
                float4 a0 = x0[k4], a1 = x1[k4], a2 = x2[k4], a3 = x3[k4];
                if (RELU) {
                    a0.x = fmaxf(a0.x, 0.f); a0.y = fmaxf(a0.y, 0.f);
                    a0.z = fmaxf(a0.z, 0.f); a0.w = fmaxf(a0.w, 0.f);
                    a1.x = fmaxf(a1.x, 0.f); a1.y = fmaxf(a1.y, 0.f);
                    a1.z = fmaxf(a1.z, 0.f); a1.w = fmaxf(a1.w, 0.f);
                    a2.x = fmaxf(a2.x, 0.f); a2.y = fmaxf(a2.y, 0.f);
                    a2.z = fmaxf(a2.z, 0.f); a2.w = fmaxf(a2.w, 0.f);
                    a3.x = fmaxf(a3.x, 0.f); a3.y = fmaxf(a3.y, 0.f);
                    a3.z = fmaxf(a3.z, 0.f); a3.w = fmaxf(a3.w, 0.f);
                }
                float w0 = Wl[(4 * k4 + 0) * 64 + lane];
                float w1 = Wl[(4 * k4 + 1) * 64 + lane];
                float w2 = Wl[(4 * k4 + 2) * 64 + lane];
                float w3 = Wl[(4 * k4 + 3) * 64 + lane];
                acc0 = fmaf(a0.x, w0, acc0); acc0 = fmaf(a0.y, w1, acc0);
                acc0 = fmaf(a0.z, w2, acc0); acc0 = fmaf(a0.w, w3, acc0);
                acc1 = fmaf(a1.x, w0, acc1); acc1 = fmaf(a1.y, w1, acc1);
                acc1 = fmaf(a1.z, w2, acc1); acc1 = fmaf(a1.w, w3, acc1);
                acc2 = fmaf(a2.x, w0, acc2); acc2 = fmaf(a2.y, w1, acc2);
                acc2 = fmaf(a2.z, w2, acc2); acc2 = fmaf(a2.w, w3, acc2);
                acc3 = fmaf(a3.x, w0, acc3); acc3 = fmaf(a3.y, w1, acc3);
                acc3 = fmaf(a3.z, w2, acc3); acc3 = fmaf(a3.w, w3, acc3);
            }
            Ts[(size_t)(r0 + 0) * 64 + lane] = acc0 * dinv[r0 + 0];
            Ts[(size_t)(r0 + 1) * 64 + lane] = acc1 * dinv[r0 + 1];
            Ts[(size_t)(r0 + 2) * 64 + lane] = acc2 * dinv[r0 + 2];
            Ts[(size_t)(r0 + 3) * 64 + lane] = acc3 * dinv[r0 + 3];
        } else {
            for (int r = r0; r < n; ++r) {
                const float4* xr = (const float4*)(X + (size_t)r * 64);
                float acc = 0.f;
#pragma unroll
                for (int k4 = 0; k4 < 16; ++k4) {
                    float4 a = xr[k4];
                    if (RELU) {
                        a.x = fmaxf(a.x, 0.f); a.y = fmaxf(a.y, 0.f);
                        a.z = fmaxf(a.z, 0.f); a.w = fmaxf(a.w, 0.f);
                    }
                    acc = fmaf(a.x, Wl[(4 * k4 + 0) * 64 + lane], acc);
                    acc = fmaf(a.y, Wl[(4 * k4 + 1) * 64 + lane], acc);
                    acc = fmaf(a.z, Wl[(4 * k4 + 2) * 64 + lane], acc);
                    acc = fmaf(a.w, Wl[(4 * k4 + 3) * 64 + lane], acc);
                }
                Ts[(size_t)r * 64 + lane] = acc * dinv[r];
            }
        }
    }
}

// One wave per dst row. 4 subgroups of 16 lanes; subgroup handles every 4th
// edge; lane's float4 covers channels 4*cl..4*cl+3. One dwordx4 VMEM instr
// serves 4 edges. A[r] = dinv[r]*(sum + Ts[r]) + b  (pure write).
__global__ void gather_kernel(const int2* __restrict__ csr,
                              const int* __restrict__ rptr,
                              const int* __restrict__ cnt,
                              const float* __restrict__ dinv,
                              const float* __restrict__ b,
                              const float* __restrict__ Ts,
                              float* __restrict__ A, int n) {
    int lane = threadIdx.x & 63;
    int r = (int)(((size_t)blockIdx.x * blockDim.x + threadIdx.x) >> 6);
    if (r >= n) return;
    int sub = lane >> 4;          // 0..3: edge subgroup
    int cl  = lane & 15;          // channel quad
    int start = rptr[r];
    int m = cnt[r];
    float4 a0 = {0.f, 0.f, 0.f, 0.f};
    float4 a1 = {0.f, 0.f, 0.f, 0.f};
    int j = sub;
    for (; j + 4 < m; j += 8) {
        int2 e0 = csr[start + j];
        int2 e1 = csr[start + j + 4];
        float w0 = __int_as_float(e0.y);
        float w1 = __int_as_float(e1.y);
        float4 t0 = *(const float4*)&Ts[(size_t)e0.x * 64 + cl * 4];
        float4 t1 = *(const float4*)&Ts[(size_t)e1.x * 64 + cl * 4];
        a0.x = fmaf(t0.x, w0, a0.x); a0.y = fmaf(t0.y, w0, a0.y);
        a0.z = fmaf(t0.z, w0, a0.z); a0.w = fmaf(t0.w, w0, a0.w);
        a1.x = fmaf(t1.x, w1, a1.x); a1.y = fmaf(t1.y, w1, a1.y);
        a1.z = fmaf(t1.z, w1, a1.z); a1.w = fmaf(t1.w, w1, a1.w);
    }
    if (j < m) {
        int2 e0 = csr[start + j];
        float w0 = __int_as_float(e0.y);
        float4 t0 = *(const float4*)&Ts[(size_t)e0.x * 64 + cl * 4];
        a0.x = fmaf(t0.x, w0, a0.x); a0.y = fmaf(t0.y, w0, a0.y);
        a0.z = fmaf(t0.z, w0, a0.z); a0.w = fmaf(t0.w, w0, a0.w);
    }
    a0.x += a1.x; a0.y += a1.y; a0.z += a1.z; a0.w += a1.w;
#pragma unroll
    for (int off = 16; off < 64; off <<= 1) {
        a0.x += __shfl_xor(a0.x, off);
        a0.y += __shfl_xor(a0.y, off);
        a0.z += __shfl_xor(a0.z, off);
        a0.w += __shfl_xor(a0.w, off);
    }
    if (sub == 0) {
        float dv = dinv[r];
        float4 ts = *(const float4*)&Ts[(size_t)r * 64 + cl * 4];
        float4 bb = *(const float4*)&b[cl * 4];
        float4 o;
        o.x = fmaf(dv, a0.x + ts.x, bb.x);
        o.y = fmaf(dv, a0.y + ts.y, bb.y);
        o.z = fmaf(dv, a0.z + ts.z, bb.z);
        o.w = fmaf(dv, a0.w + ts.w, bb.w);
        *(float4*)&A[(size_t)r * 64 + cl * 4] = o;
    }
}

// Thread per node: sv = relu(h @ Wr0 + br0) @ Wr1 + br1.
// batch is sorted -> wave-segmented suffix reduction, heads do the atomics.
__global__ void readout_kernel(const float* __restrict__ H,
                               const float* __restrict__ Wr0,
                               const float* __restrict__ br0,
                               const float* __restrict__ Wr1,
                               const float* __restrict__ br1,
                               const int* __restrict__ batch,
                               float* __restrict__ gsum,
                               float* __restrict__ gcnt, int n) {
    __shared__ float Ws[64 * 32];
    __shared__ float w1s[32];
    for (int i = threadIdx.x; i < 64 * 32; i += blockDim.x) Ws[i] = Wr0[i];
    if (threadIdx.x < 32) w1s[threadIdx.x] = Wr1[threadIdx.x];
    __syncthreads();
    int r = blockIdx.x * blockDim.x + threadIdx.x;
    int lane = threadIdx.x & 63;
    float sv = 0.0f;
    int g = -1;
    if (r < n) {
        float h[64];
        const float4* hr = (const float4*)(H + (size_t)r * 64);
#pragma unroll
        for (int i = 0; i < 16; ++i) {
            float4 v = hr[i];
            h[4 * i + 0] = v.x; h[4 * i + 1] = v.y;
            h[4 * i + 2] = v.z; h[4 * i + 3] = v.w;
        }
        float ssum = 0.0f;
#pragma unroll 1
        for (int jg = 0; jg < 8; ++jg) {
            float a0 = br0[jg * 4 + 0], a1 = br0[jg * 4 + 1];
            float a2 = br0[jg * 4 + 2], a3 = br0[jg * 4 + 3];
#pragma unroll
            for (int k = 0; k < 64; ++k) {
                const float4 wv = *(const float4*)&Ws[k * 32 + jg * 4];
                a0 = fmaf(h[k], wv.x, a0);
                a1 = fmaf(h[k], wv.y, a1);
                a2 = fmaf(h[k], wv.z, a2);
                a3 = fmaf(h[k], wv.w, a3);
            }
            a0 = fmaxf(a0, 0.0f); a1 = fmaxf(a1, 0.0f);
            a2 = fmaxf(a2, 0.0f); a3 = fmaxf(a3, 0.0f);
            ssum += a0 * w1s[jg * 4 + 0] + a1 * w1s[jg * 4 + 1] +
                    a2 * w1s[jg * 4 + 2] + a3 * w1s[jg * 4 + 3];
        }
        sv = ssum + br1[0];
        g = batch[r];
    }
    float c = (r < n) ? 1.0f : 0.0f;
#pragma unroll
    for (int off = 1; off < 64; off <<= 1) {
        int   og = __shfl_down(g, off);
        float ov = __shfl_down(sv, off);
        float oc = __shfl_down(c, off);
        if ((lane + off) < 64 && og == g) { sv += ov; c += oc; }
    }
    int gprev = __shfl_up(g, 1);
    bool head = (lane == 0) || (gprev != g);
    if (head && g >= 0) {
        atomicAdd(&gsum[g], sv);
        atomicAdd(&gcnt[g], c);
    }
}

__global__ void pool_fin_kernel(const float* __restrict__ gsum,
                                const float* __restrict__ gcnt,
                                float* __restrict__ out, int ng) {
    int g = blockIdx.x * blockDim.x + threadIdx.x;
    if (g < ng) out[g] = gsum[g] / fmaxf(gcnt[g], 1.0f);
}

extern "C" void kernel_launch(void* const* d_in, const int* in_sizes, int n_in,
                              void* d_out, int out_size, void* d_ws, size_t ws_size,
                              hipStream_t stream) {
    const float* x    = (const float*)d_in[0];
    const int*   ei   = (const int*)d_in[1];
    const float* ew   = (const float*)d_in[2];
    const int*   batch= (const int*)d_in[3];
    const float* W0   = (const float*)d_in[4];
    const float* b0   = (const float*)d_in[5];
    const float* W1   = (const float*)d_in[6];
    const float* b1   = (const float*)d_in[7];
    const float* W2   = (const float*)d_in[8];
    const float* b2   = (const float*)d_in[9];
    const float* Wr0  = (const float*)d_in[10];
    const float* br0  = (const float*)d_in[11];
    const float* Wr1  = (const float*)d_in[12];
    const float* br1  = (const float*)d_in[13];
    float* out = (float*)d_out;

    int n  = in_sizes[0] / 64;   // 100000
    int ne = in_sizes[1] / 2;    // 1600000
    int ng = out_size;           // 256
    const int* srcv = ei;
    const int* dstv = ei + ne;
    int nbk = (n + 255) >> 8;    // 391

    char* ws = (char*)d_ws;
    size_t off = 0;
    auto alloc = [&](size_t bytes) {
        void* p = ws + off;
        off += (bytes + 255) & ~(size_t)255;
        return p;
    };
    float* Ts     = (float*)alloc((size_t)n * 64 * sizeof(float));
    float* A      = (float*)alloc((size_t)n * 64 * sizeof(float));
    float* dinv   = (float*)alloc((size_t)n * sizeof(float));
    int*   cnt    = (int*)alloc((size_t)n * sizeof(int));
    int*   rptr   = (int*)alloc((size_t)n * sizeof(int));
    int*   bcnt   = (int*)alloc(520 * sizeof(int));
    int*   bbase  = (int*)alloc(520 * sizeof(int));
    int*   gcur   = (int*)alloc(520 * sizeof(int));
    int2*  csr    = (int2*)alloc((size_t)ne * sizeof(int2));
    float* gsum   = (float*)alloc((size_t)ng * sizeof(float));
    float* gcnt   = (float*)alloc((size_t)ng * sizeof(float));
    // packed aliases Ts: consumed by bucket_build before first gemm writes Ts.
    int2*  packed = (int2*)Ts;
    (void)ws_size;

    hipMemsetAsync(bcnt, 0, 520 * sizeof(int), stream);
    hipMemsetAsync(gsum, 0, (size_t)ng * sizeof(float), stream);
    hipMemsetAsync(gcnt, 0, (size_t)ng * sizeof(float), stream);

    hist_kernel<<<256, 256, 0, stream>>>(dstv, bcnt, ne);
    bscan_kernel<<<1, 512, 0, stream>>>(bcnt, bbase, gcur, nbk, ne);
    scatterB_kernel<<<200, 256, 0, stream>>>(srcv, dstv, ew, gcur, packed, ne);
    bucket_build_kernel<<<nbk, 256, 0, stream>>>(packed, bbase, rptr, cnt,
                                                 dinv, csr, n);

    const int gemm_blocks = 1024;
    unsigned gat_blocks = (unsigned)(((size_t)n * 64 + 255) / 256);

    gemm_lds_kernel<false><<<gemm_blocks, 256, 0, stream>>>(x, W0, dinv, Ts, n);
    gather_kernel<<<gat_blocks, 256, 0, stream>>>(csr, rptr, cnt, dinv, b0, Ts, A, n);

    gemm_lds_kernel<true><<<gemm_blocks, 256, 0, stream>>>(A, W1, dinv, Ts, n);
    gather_kernel<<<gat_blocks, 256, 0, stream>>>(csr, rptr, cnt, dinv, b1, Ts, A, n);

    gemm_lds_kernel<true><<<gemm_blocks, 256, 0, stream>>>(A, W2, dinv, Ts, n);
    gather_kernel<<<gat_blocks, 256, 0, stream>>>(csr, rptr, cnt, dinv, b2, Ts, A, n);

    readout_kernel<<<(n + 255) / 256, 256, 0, stream>>>(A, Wr0, br0, Wr1, br1,
                                                        batch, gsum, gcnt, n);
    pool_fin_kernel<<<(ng + 255) / 256, 256, 0, stream>>>(gsum, gcnt, out, ng);
}